// Round 8
// baseline (284.796 us; speedup 1.0000x reference)
//
#include <hip/hip_runtime.h>
#include <math.h>

#define IDIM 32
#define KNN 16
#define NPTS 8192
#define NBATCH 16
#define PPB 16                      // points per block
#define CLAMPV 1.9f
#define TWO_OVER_PI 0.63661977236758134f

typedef __attribute__((ext_vector_type(8))) short bf16x8;   // 8 bf16 = 4 VGPR (MFMA A/B)
typedef __attribute__((ext_vector_type(4))) float f32x4;    // MFMA C/D
typedef __attribute__((ext_vector_type(2))) short s16x2;

// Compiler-friendly bf16 pack: scalar __bf16 casts fuse to v_cvt_pk_bf16_f32.
__device__ __forceinline__ unsigned pk2(float a, float b) {
    union { __bf16 h[2]; unsigned u; } r;
    r.h[0] = (__bf16)a; r.h[1] = (__bf16)b;
    return r.u;
}
__device__ __forceinline__ unsigned short f2bf(float f) {
    union { __bf16 h; unsigned short u; } r; r.h = (__bf16)f; return r.u;
}

// ReLU on a packed bf16 pair: IEEE sign-magnitude => per-half smax(x,0) == relu.
__device__ __forceinline__ unsigned relu2(unsigned p) {
    s16x2 v; __builtin_memcpy(&v, &p, 4);
    s16x2 z = {0, 0};
    s16x2 m = __builtin_elementwise_max(v, z);
    unsigned r; __builtin_memcpy(&r, &m, 4);
    return r;
}

// Volatile LDS f32x4 load: NOT hoisted/CSE'd, so the value is a fresh last-use
// C-operand each MFMA -> register allocator does D=C in place (no v_mov copies).
__device__ __forceinline__ f32x4 ldsv4(const float* p) {
    return *(const volatile f32x4*)p;
}

// Raw ds_swizzle (BitMode XOR) — 1 DS op, no lane-index VALU math.
template<int PAT>
__device__ __forceinline__ float swzf(float v) {
    return __int_as_float(__builtin_amdgcn_ds_swizzle(__float_as_int(v), PAT));
}
__device__ __forceinline__ float red_max16(float o) {
    o = fmaxf(o, swzf<0x041F>(o));   // xor 1
    o = fmaxf(o, swzf<0x081F>(o));   // xor 2
    o = fmaxf(o, swzf<0x101F>(o));   // xor 4
    o = fmaxf(o, swzf<0x201F>(o));   // xor 8
    return o;
}
__device__ __forceinline__ float red_sum16(float o) {
    o += swzf<0x041F>(o); o += swzf<0x081F>(o);
    o += swzf<0x101F>(o); o += swzf<0x201F>(o);
    return o;
}

// ---------------------------------------------------------------------------
// Precompute MFMA A-fragments (bf16) for all 4 networks into ws.
// mfma_f32_16x16x32_bf16 A-layout: lane l holds A[row=l&15][k=(l>>4)*8+j], j=0..7.
// Frag f element order in ws: f*512 + lane*8 + j.
// Frag table per net u (fb = u*14):
//   fb+c        (c=0..3)        : L1  A_c[row][k] = W1f[k][16c+row]
//   fb+4+2c+kc  (c=0..3,kc=0..1): L2  A[row][k]   = W2[kc*32+k][16c+row]
//   fb+12+kc    (kc=0..1)       : L3  A[row][k]   = W3[kc*32+k][row]
// W1f rows: k<16 -> WA[k]=W1[k]-W1[32+k]; k>=16 -> WB[k-16]=W1[k]+W1[k+16]
// ---------------------------------------------------------------------------
__global__ void prep_frags(const float* __restrict__ W1, const float* __restrict__ W2,
                           const float* __restrict__ W3, unsigned short* __restrict__ wsb) {
    int e = blockIdx.x * 256 + threadIdx.x;       // 0 .. 56*512-1
    if (e >= 56 * 512) return;
    int f = e >> 9, idx = e & 511;
    int lane = idx >> 3, j = idx & 7;
    int row = lane & 15, g = lane >> 4;
    int k = g * 8 + j;                            // 0..31
    int u = f / 14, t = f % 14;
    float val;
    if (t < 4) {
        int h = 16 * t + row;
        const float* w = W1 + u * 3072;           // (48,64) row-major
        val = (k < 16) ? (w[k * 64 + h] - w[(32 + k) * 64 + h])
                       : (w[k * 64 + h] + w[(k + 16) * 64 + h]);
    } else if (t < 12) {
        int c = (t - 4) >> 1, kc = (t - 4) & 1;
        val = W2[u * 4096 + (kc * 32 + k) * 64 + 16 * c + row];
    } else {
        int kc = t - 12;
        val = W3[u * 1024 + (kc * 32 + k) * 16 + row];
    }
    wsb[e] = f2bf(val);
}

// ---------------------------------------------------------------------------
// z[b,n,d] = x[b,n,31-d]*exp(logs[d]) + bias[d]; init log_det[b].
// ---------------------------------------------------------------------------
__global__ void affine_rev(const float* __restrict__ x, const float* __restrict__ logs,
                           const float* __restrict__ bias, float* __restrict__ out) {
    __shared__ float ssc[IDIM], sbi[IDIM];
    int tid = threadIdx.x;
    if (tid < IDIM) { ssc[tid] = expf(logs[tid]); sbi[tid] = bias[tid]; }
    __syncthreads();
    size_t p = (size_t)blockIdx.x * blockDim.x + tid;
    if (p < (size_t)NBATCH * NPTS) {
        const float4* xr = (const float4*)(x + p * IDIM);
        float xv[IDIM];
#pragma unroll
        for (int q = 0; q < 8; ++q) {
            float4 v = xr[q];
            xv[q * 4 + 0] = v.x; xv[q * 4 + 1] = v.y; xv[q * 4 + 2] = v.z; xv[q * 4 + 3] = v.w;
        }
        float4* zr = (float4*)(out + p * IDIM);
#pragma unroll
        for (int q = 0; q < 8; ++q) {
            float4 v;
            v.x = xv[31 - (q * 4 + 0)] * ssc[q * 4 + 0] + sbi[q * 4 + 0];
            v.y = xv[31 - (q * 4 + 1)] * ssc[q * 4 + 1] + sbi[q * 4 + 1];
            v.z = xv[31 - (q * 4 + 2)] * ssc[q * 4 + 2] + sbi[q * 4 + 2];
            v.w = xv[31 - (q * 4 + 3)] * ssc[q * 4 + 3] + sbi[q * 4 + 3];
            zr[q] = v;
        }
    }
    if (blockIdx.x == 0 && tid < NBATCH) {
        float sl = 0.f;
#pragma unroll
        for (int d = 0; d < IDIM; ++d) sl += logs[d];
        out[(size_t)NBATCH * NPTS * IDIM + tid] = sl * (float)NPTS;
    }
}

// ---------------------------------------------------------------------------
// MFMA conv kernel, 2-pt ILP + feature prefetch.
// v8: biases live in LDS and are ds_read_b128'd directly into the accumulator
// as a fresh last-use C operand (kills ~72 v_mov/pair of C-copies); knn
// indices pre-staged to LDS (kills 16 global index loads/lane + addressing).
// ---------------------------------------------------------------------------
__global__ __launch_bounds__(256, 3)
void knn_mfma(const int* __restrict__ knn, const unsigned short* __restrict__ wsb,
              const float* __restrict__ B1, const float* __restrict__ B2,
              const float* __restrict__ B3, float* __restrict__ out) {
    __shared__ unsigned long long hq[4 * 2 * 272];        // [wave][pt A/B][16 cols x 17]
    __shared__ float stg[PPB * 4 * 16];                   // [pt][net][dim]
    __shared__ float ldsum[16];
    __shared__ float sbias[4 * 144];                      // per net: b1(64) b2(64) b3(16)
    __shared__ int   sidx[PPB * KNN];                     // 256 knn indices for this block

    const int tid = threadIdx.x;
    const int u = tid >> 6, lane = tid & 63;
    const int g = lane >> 4, x = lane & 15;
    const int pbase = blockIdx.x * PPB;
    const int bb = pbase >> 13;                           // batch (PPB divides 8192)

    // --- stage biases + knn indices (one coalesced pass) ---
    {
        int un = tid >> 6, r = tid & 63;
        sbias[un * 144 + r]      = B1[tid];
        sbias[un * 144 + 64 + r] = B2[tid];
        if (tid < 64) sbias[(tid >> 4) * 144 + 128 + (tid & 15)] = B3[tid];
        sidx[tid] = knn[(size_t)pbase * KNN + tid];
    }
    __syncthreads();

    // --- weight fragments (persist across the point loop) ---
    bf16x8 a1[4], a2k0[4], a2k1[4], a30, a31;
    const int fb = u * 14;
#pragma unroll
    for (int c = 0; c < 4; ++c)
        a1[c] = *(const bf16x8*)(wsb + (size_t)(fb + c) * 512 + lane * 8);
#pragma unroll
    for (int c = 0; c < 4; ++c) {
        a2k0[c] = *(const bf16x8*)(wsb + (size_t)(fb + 4 + 2 * c + 0) * 512 + lane * 8);
        a2k1[c] = *(const bf16x8*)(wsb + (size_t)(fb + 4 + 2 * c + 1) * 512 + lane * 8);
    }
    a30 = *(const bf16x8*)(wsb + (size_t)(fb + 12) * 512 + lane * 8);
    a31 = *(const bf16x8*)(wsb + (size_t)(fb + 13) * 512 + lane * 8);

    // --- bias LDS pointers: lane owns rows 16c+4g..+3 (broadcast across x) ---
    const float* sb1 = sbias + u * 144 + 4 * g;           // + 16*c
    const float* sb2 = sbias + u * 144 + 64 + 4 * g;      // + 16*c
    const float* sb3 = sbias + u * 144 + 128 + 4 * g;

    // --- LDS staging offsets in u64 units; swizzle = ((x&7)<<4 bytes) >> 3 ---
    const int baseA = (u * 2 + 0) * 272;
    const int baseB = (u * 2 + 1) * 272;
    const int swq = (x & 7) << 1;
    int woq[4];
#pragma unroll
    for (int c = 0; c < 4; ++c) woq[c] = x * 17 + ((4 * c + g) ^ swq);
    const int rq0 = x * 17 + ((2 * g) ^ swq);
    const int rq1 = x * 17 + ((8 + 2 * g) ^ swq);

    const int off = (g & 1) * 8;
    const float* zb = out + (size_t)bb * NPTS * IDIM;     // batch base
    const int baseRow = pbase & (NPTS - 1);               // local row of pbase

    // --- prologue: features for pair 0 ---
    float4 pA0, pA1, pB0, pB1, nA0, nA1, nB0, nB1;
    {
        int iA0 = sidx[x], iB0 = sidx[16 + x];
        const float* rpA = zb + (size_t)((g < 2) ? baseRow : iA0) * IDIM;
        pA0 = *(const float4*)(rpA + off); pA1 = *(const float4*)(rpA + off + 4);
        const float* rpB = zb + (size_t)((g < 2) ? (baseRow + 1) : iB0) * IDIM;
        pB0 = *(const float4*)(rpB + off); pB1 = *(const float4*)(rpB + off + 4);
    }

#pragma unroll 1
    for (int pp = 0; pp < PPB / 2; ++pp) {
        // prefetch next pair's features (indices from LDS, just-in-time)
        if (pp < PPB / 2 - 1) {
            int iA1 = sidx[(2 * pp + 2) * 16 + x];
            int iB1 = sidx[(2 * pp + 3) * 16 + x];
            const float* rpA = zb + (size_t)((g < 2) ? (baseRow + 2 * pp + 2) : iA1) * IDIM;
            nA0 = *(const float4*)(rpA + off); nA1 = *(const float4*)(rpA + off + 4);
            const float* rpB = zb + (size_t)((g < 2) ? (baseRow + 2 * pp + 3) : iB1) * IDIM;
            nB0 = *(const float4*)(rpB + off); nB1 = *(const float4*)(rpB + off + 4);
        }

        // pack features (v_cvt_pk_bf16_f32 pairs)
        union { bf16x8 v; unsigned w[4]; } efA, efB;
        efA.w[0] = pk2(pA0.x, pA0.y); efA.w[1] = pk2(pA0.z, pA0.w);
        efA.w[2] = pk2(pA1.x, pA1.y); efA.w[3] = pk2(pA1.z, pA1.w);
        efB.w[0] = pk2(pB0.x, pB0.y); efB.w[1] = pk2(pB0.z, pB0.w);
        efB.w[2] = pk2(pB1.x, pB1.y); efB.w[3] = pk2(pB1.z, pB1.w);

        // ---- L1 (bias ds_read -> in-place C) ----
        f32x4 aA[4], aB[4];
#pragma unroll
        for (int c = 0; c < 4; ++c)
            aA[c] = __builtin_amdgcn_mfma_f32_16x16x32_bf16(a1[c], efA.v, ldsv4(sb1 + 16 * c), 0, 0, 0);
#pragma unroll
        for (int c = 0; c < 4; ++c)
            aB[c] = __builtin_amdgcn_mfma_f32_16x16x32_bf16(a1[c], efB.v, ldsv4(sb1 + 16 * c), 0, 0, 0);
#pragma unroll
        for (int c = 0; c < 4; ++c) {
            union { unsigned w[2]; unsigned long long q; } qa;
            qa.w[0] = relu2(pk2(aA[c][0], aA[c][1]));
            qa.w[1] = relu2(pk2(aA[c][2], aA[c][3]));
            hq[baseA + woq[c]] = qa.q;
        }
#pragma unroll
        for (int c = 0; c < 4; ++c) {
            union { unsigned w[2]; unsigned long long q; } qb;
            qb.w[0] = relu2(pk2(aB[c][0], aB[c][1]));
            qb.w[1] = relu2(pk2(aB[c][2], aB[c][3]));
            hq[baseB + woq[c]] = qb.q;
        }

        // ---- read h1, L2 (bias ds_read -> in-place C) ----
        union { bf16x8 v; unsigned long long q[2]; } h0A, h1A, h0B, h1B;
        h0A.q[0] = hq[baseA + rq0]; h0A.q[1] = hq[baseA + rq0 + 1];
        h1A.q[0] = hq[baseA + rq1]; h1A.q[1] = hq[baseA + rq1 + 1];
        h0B.q[0] = hq[baseB + rq0]; h0B.q[1] = hq[baseB + rq0 + 1];
        h1B.q[0] = hq[baseB + rq1]; h1B.q[1] = hq[baseB + rq1 + 1];
        f32x4 cA[4], cB[4];
#pragma unroll
        for (int c = 0; c < 4; ++c) {
            cA[c] = __builtin_amdgcn_mfma_f32_16x16x32_bf16(a2k0[c], h0A.v, ldsv4(sb2 + 16 * c), 0, 0, 0);
            cB[c] = __builtin_amdgcn_mfma_f32_16x16x32_bf16(a2k0[c], h0B.v, ldsv4(sb2 + 16 * c), 0, 0, 0);
        }
#pragma unroll
        for (int c = 0; c < 4; ++c) {
            cA[c] = __builtin_amdgcn_mfma_f32_16x16x32_bf16(a2k1[c], h1A.v, cA[c], 0, 0, 0);
            cB[c] = __builtin_amdgcn_mfma_f32_16x16x32_bf16(a2k1[c], h1B.v, cB[c], 0, 0, 0);
        }
#pragma unroll
        for (int c = 0; c < 4; ++c) {
            union { unsigned w[2]; unsigned long long q; } qa;
            qa.w[0] = relu2(pk2(cA[c][0], cA[c][1]));
            qa.w[1] = relu2(pk2(cA[c][2], cA[c][3]));
            hq[baseA + woq[c]] = qa.q;
        }
#pragma unroll
        for (int c = 0; c < 4; ++c) {
            union { unsigned w[2]; unsigned long long q; } qb;
            qb.w[0] = relu2(pk2(cB[c][0], cB[c][1]));
            qb.w[1] = relu2(pk2(cB[c][2], cB[c][3]));
            hq[baseB + woq[c]] = qb.q;
        }

        // ---- read h2, L3 (bias ds_read -> in-place C) ----
        union { bf16x8 v; unsigned long long q[2]; } g0A, g1A, g0B, g1B;
        g0A.q[0] = hq[baseA + rq0]; g0A.q[1] = hq[baseA + rq0 + 1];
        g1A.q[0] = hq[baseA + rq1]; g1A.q[1] = hq[baseA + rq1 + 1];
        g0B.q[0] = hq[baseB + rq0]; g0B.q[1] = hq[baseB + rq0 + 1];
        g1B.q[0] = hq[baseB + rq1]; g1B.q[1] = hq[baseB + rq1 + 1];
        f32x4 oA, oB;
        oA = __builtin_amdgcn_mfma_f32_16x16x32_bf16(a30, g0A.v, ldsv4(sb3), 0, 0, 0);
        oB = __builtin_amdgcn_mfma_f32_16x16x32_bf16(a30, g0B.v, ldsv4(sb3), 0, 0, 0);
        oA = __builtin_amdgcn_mfma_f32_16x16x32_bf16(a31, g1A.v, oA, 0, 0, 0);
        oB = __builtin_amdgcn_mfma_f32_16x16x32_bf16(a31, g1B.v, oB, 0, 0, 0);

        // max over neighbors: raw ds_swizzle XOR tree
        float oA0 = red_max16(oA[0]), oA1 = red_max16(oA[1]);
        float oA2 = red_max16(oA[2]), oA3 = red_max16(oA[3]);
        float oB0 = red_max16(oB[0]), oB1 = red_max16(oB[1]);
        float oB2 = red_max16(oB[2]), oB3 = red_max16(oB[3]);

        if (x == 0) {
            *(float4*)&stg[((2 * pp + 0) * 4 + u) * 16 + 4 * g] = make_float4(oA0, oA1, oA2, oA3);
            *(float4*)&stg[((2 * pp + 1) * 4 + u) * 16 + 4 * g] = make_float4(oB0, oB1, oB2, oB3);
        }

        // rotate prefetched features
        pA0 = nA0; pA1 = nA1; pB0 = nB0; pB1 = nB1;
    }
    __syncthreads();

    // --- epilogue: z2 update + log_det (one atomic per block) ---
    {
        const int pu = u * 4 + g;                  // 0..15
        const int prow = pbase + pu;
        const size_t zoff = (size_t)prow * IDIM + 16 + x;
        float z2v = out[zoff];
        float s1 = stg[(pu * 4 + 0) * 16 + x];
        float t1 = stg[(pu * 4 + 1) * 16 + x];
        float s2 = stg[(pu * 4 + 2) * 16 + x];
        float t2 = stg[(pu * 4 + 3) * 16 + x];
        float sc1 = CLAMPV * TWO_OVER_PI * atanf(s1 * (1.0f / CLAMPV));
        float sc2 = CLAMPV * TWO_OVER_PI * atanf(s2 * (1.0f / CLAMPV));
        z2v = z2v * expf(sc1) + t1;
        z2v = z2v * expf(sc2) + t2;
        out[zoff] = z2v;
        float ss = red_sum16(sc1 + sc2);
        if (x == 0) ldsum[pu] = ss;
    }
    __syncthreads();
    if (tid == 0) {
        float tot = 0.f;
#pragma unroll
        for (int i = 0; i < 16; ++i) tot += ldsum[i];
        atomicAdd(out + (size_t)NBATCH * NPTS * IDIM + bb, tot);
    }
}

extern "C" void kernel_launch(void* const* d_in, const int* in_sizes, int n_in,
                              void* d_out, int out_size, void* d_ws, size_t ws_size,
                              hipStream_t stream) {
    const float* x    = (const float*)d_in[0];
    const int*   knn  = (const int*)d_in[1];
    const float* logs = (const float*)d_in[2];
    const float* bias = (const float*)d_in[3];
    const float* W1   = (const float*)d_in[4];
    const float* b1   = (const float*)d_in[5];
    const float* W2   = (const float*)d_in[6];
    const float* b2   = (const float*)d_in[7];
    const float* W3   = (const float*)d_in[8];
    const float* b3   = (const float*)d_in[9];
    float* out = (float*)d_out;
    unsigned short* wsb = (unsigned short*)d_ws;   // 56 frags * 1024 B = 57344 B

    hipLaunchKernelGGL(prep_frags, dim3(112), dim3(256), 0, stream, W1, W2, W3, wsb);
    hipLaunchKernelGGL(affine_rev, dim3(512), dim3(256), 0, stream, x, logs, bias, out);
    hipLaunchKernelGGL(knn_mfma, dim3((NBATCH * NPTS) / PPB), dim3(256), 0, stream,
                       knn, wsb, b1, b2, b3, out);
}

// Round 9
// 216.067 us; speedup vs baseline: 1.3181x; 1.3181x over previous
//
#include <hip/hip_runtime.h>
#include <math.h>

#define IDIM 32
#define KNN 16
#define NPTS 8192
#define NBATCH 16
#define PPB 16                      // points per block
#define CLAMPV 1.9f
#define TWO_OVER_PI 0.63661977236758134f

typedef __attribute__((ext_vector_type(8))) short bf16x8;   // 8 bf16 = 4 VGPR (MFMA A/B)
typedef __attribute__((ext_vector_type(4))) float f32x4;    // MFMA C/D
typedef __attribute__((ext_vector_type(2))) short s16x2;

// Compiler-friendly bf16 pack: scalar __bf16 casts fuse to v_cvt_pk_bf16_f32.
__device__ __forceinline__ unsigned pk2(float a, float b) {
    union { __bf16 h[2]; unsigned u; } r;
    r.h[0] = (__bf16)a; r.h[1] = (__bf16)b;
    return r.u;
}
__device__ __forceinline__ unsigned short f2bf(float f) {
    union { __bf16 h; unsigned short u; } r; r.h = (__bf16)f; return r.u;
}

// ReLU on a packed bf16 pair: IEEE sign-magnitude => per-half smax(x,0) == relu.
__device__ __forceinline__ unsigned relu2(unsigned p) {
    s16x2 v; __builtin_memcpy(&v, &p, 4);
    s16x2 z = {0, 0};
    s16x2 m = __builtin_elementwise_max(v, z);
    unsigned r; __builtin_memcpy(&r, &m, 4);
    return r;
}

// Raw ds_swizzle (BitMode XOR) — 1 DS op, no lane-index VALU math.
template<int PAT>
__device__ __forceinline__ float swzf(float v) {
    return __int_as_float(__builtin_amdgcn_ds_swizzle(__float_as_int(v), PAT));
}
__device__ __forceinline__ float red_max16(float o) {
    o = fmaxf(o, swzf<0x041F>(o));   // xor 1
    o = fmaxf(o, swzf<0x081F>(o));   // xor 2
    o = fmaxf(o, swzf<0x101F>(o));   // xor 4
    o = fmaxf(o, swzf<0x201F>(o));   // xor 8
    return o;
}
__device__ __forceinline__ float red_sum16(float o) {
    o += swzf<0x041F>(o); o += swzf<0x081F>(o);
    o += swzf<0x101F>(o); o += swzf<0x201F>(o);
    return o;
}

// ---------------------------------------------------------------------------
// Precompute MFMA A-fragments (bf16) for all 4 networks into ws.
// mfma_f32_16x16x32_bf16 A-layout: lane l holds A[row=l&15][k=(l>>4)*8+j], j=0..7.
// Frag f element order in ws: f*512 + lane*8 + j.
// Frag table per net u (fb = u*14):
//   fb+c        (c=0..3)        : L1  A_c[row][k] = W1f[k][16c+row]
//   fb+4+2c+kc  (c=0..3,kc=0..1): L2  A[row][k]   = W2[kc*32+k][16c+row]
//   fb+12+kc    (kc=0..1)       : L3  A[row][k]   = W3[kc*32+k][row]
// W1f rows: k<16 -> WA[k]=W1[k]-W1[32+k]; k>=16 -> WB[k-16]=W1[k]+W1[k+16]
// ---------------------------------------------------------------------------
__global__ void prep_frags(const float* __restrict__ W1, const float* __restrict__ W2,
                           const float* __restrict__ W3, unsigned short* __restrict__ wsb) {
    int e = blockIdx.x * 256 + threadIdx.x;       // 0 .. 56*512-1
    if (e >= 56 * 512) return;
    int f = e >> 9, idx = e & 511;
    int lane = idx >> 3, j = idx & 7;
    int row = lane & 15, g = lane >> 4;
    int k = g * 8 + j;                            // 0..31
    int u = f / 14, t = f % 14;
    float val;
    if (t < 4) {
        int h = 16 * t + row;
        const float* w = W1 + u * 3072;           // (48,64) row-major
        val = (k < 16) ? (w[k * 64 + h] - w[(32 + k) * 64 + h])
                       : (w[k * 64 + h] + w[(k + 16) * 64 + h]);
    } else if (t < 12) {
        int c = (t - 4) >> 1, kc = (t - 4) & 1;
        val = W2[u * 4096 + (kc * 32 + k) * 64 + 16 * c + row];
    } else {
        int kc = t - 12;
        val = W3[u * 1024 + (kc * 32 + k) * 16 + row];
    }
    wsb[e] = f2bf(val);
}

// ---------------------------------------------------------------------------
// z[b,n,d] = x[b,n,31-d]*exp(logs[d]) + bias[d]; init log_det[b].
// ---------------------------------------------------------------------------
__global__ void affine_rev(const float* __restrict__ x, const float* __restrict__ logs,
                           const float* __restrict__ bias, float* __restrict__ out) {
    __shared__ float ssc[IDIM], sbi[IDIM];
    int tid = threadIdx.x;
    if (tid < IDIM) { ssc[tid] = expf(logs[tid]); sbi[tid] = bias[tid]; }
    __syncthreads();
    size_t p = (size_t)blockIdx.x * blockDim.x + tid;
    if (p < (size_t)NBATCH * NPTS) {
        const float4* xr = (const float4*)(x + p * IDIM);
        float xv[IDIM];
#pragma unroll
        for (int q = 0; q < 8; ++q) {
            float4 v = xr[q];
            xv[q * 4 + 0] = v.x; xv[q * 4 + 1] = v.y; xv[q * 4 + 2] = v.z; xv[q * 4 + 3] = v.w;
        }
        float4* zr = (float4*)(out + p * IDIM);
#pragma unroll
        for (int q = 0; q < 8; ++q) {
            float4 v;
            v.x = xv[31 - (q * 4 + 0)] * ssc[q * 4 + 0] + sbi[q * 4 + 0];
            v.y = xv[31 - (q * 4 + 1)] * ssc[q * 4 + 1] + sbi[q * 4 + 1];
            v.z = xv[31 - (q * 4 + 2)] * ssc[q * 4 + 2] + sbi[q * 4 + 2];
            v.w = xv[31 - (q * 4 + 3)] * ssc[q * 4 + 3] + sbi[q * 4 + 3];
            zr[q] = v;
        }
    }
    if (blockIdx.x == 0 && tid < NBATCH) {
        float sl = 0.f;
#pragma unroll
        for (int d = 0; d < IDIM; ++d) sl += logs[d];
        out[(size_t)NBATCH * NPTS * IDIM + tid] = sl * (float)NPTS;
    }
}

// ---------------------------------------------------------------------------
// MFMA conv kernel, 2-pt ILP + feature prefetch. r9 = r7 structure (biases in
// registers — MFMA C/D are distinct operand fields, no copies) + knn indices
// staged in LDS (r8's good half) + #pragma unroll 2 on the pair loop
// (cross-iteration ILP; no barriers in loop so scheduler can interleave
// pair p+1's L1 with pair p's L3/reduce) + s_setprio around MFMA clusters.
// ---------------------------------------------------------------------------
__global__ __launch_bounds__(256, 3)
void knn_mfma(const int* __restrict__ knn, const unsigned short* __restrict__ wsb,
              const float* __restrict__ B1, const float* __restrict__ B2,
              const float* __restrict__ B3, float* __restrict__ out) {
    __shared__ unsigned long long hq[4 * 2 * 272];        // [wave][pt A/B][16 cols x 17]
    __shared__ float stg[PPB * 4 * 16];                   // [pt][net][dim]
    __shared__ float ldsum[16];
    __shared__ int   sidx[PPB * KNN];                     // 256 knn indices for this block

    const int tid = threadIdx.x;
    const int u = tid >> 6, lane = tid & 63;
    const int g = lane >> 4, x = lane & 15;
    const int pbase = blockIdx.x * PPB;
    const int bb = pbase >> 13;                           // batch (PPB divides 8192)

    // --- stage knn indices (one coalesced load per thread) ---
    sidx[tid] = knn[(size_t)pbase * KNN + tid];

    // --- weight fragments (persist across the point loop) ---
    bf16x8 a1[4], a2k0[4], a2k1[4], a30, a31;
    const int fb = u * 14;
#pragma unroll
    for (int c = 0; c < 4; ++c)
        a1[c] = *(const bf16x8*)(wsb + (size_t)(fb + c) * 512 + lane * 8);
#pragma unroll
    for (int c = 0; c < 4; ++c) {
        a2k0[c] = *(const bf16x8*)(wsb + (size_t)(fb + 4 + 2 * c + 0) * 512 + lane * 8);
        a2k1[c] = *(const bf16x8*)(wsb + (size_t)(fb + 4 + 2 * c + 1) * 512 + lane * 8);
    }
    a30 = *(const bf16x8*)(wsb + (size_t)(fb + 12) * 512 + lane * 8);
    a31 = *(const bf16x8*)(wsb + (size_t)(fb + 13) * 512 + lane * 8);

    // --- biases as persistent MFMA C-operands: lane owns rows 16c+4g..+3 ---
    f32x4 b1v[4], b2v[4], b3v;
#pragma unroll
    for (int c = 0; c < 4; ++c) {
        b1v[c] = *(const f32x4*)(B1 + u * 64 + 16 * c + 4 * g);
        b2v[c] = *(const f32x4*)(B2 + u * 64 + 16 * c + 4 * g);
    }
    b3v = *(const f32x4*)(B3 + u * 16 + 4 * g);

    // --- LDS staging offsets in u64 units; swizzle = ((x&7)<<4 bytes) >> 3 ---
    const int baseA = (u * 2 + 0) * 272;
    const int baseB = (u * 2 + 1) * 272;
    const int swq = (x & 7) << 1;
    int woq[4];
#pragma unroll
    for (int c = 0; c < 4; ++c) woq[c] = x * 17 + ((4 * c + g) ^ swq);
    const int rq0 = x * 17 + ((2 * g) ^ swq);
    const int rq1 = x * 17 + ((8 + 2 * g) ^ swq);

    const int off = (g & 1) * 8;
    const float* zb = out + (size_t)bb * NPTS * IDIM;     // batch base
    const int baseRow = pbase & (NPTS - 1);               // local row of pbase

    __syncthreads();                                      // sidx visible

    // --- prologue: features for pair 0 ---
    float4 pA0, pA1, pB0, pB1, nA0, nA1, nB0, nB1;
    {
        int iA0 = sidx[x], iB0 = sidx[16 + x];
        const float* rpA = zb + (size_t)((g < 2) ? baseRow : iA0) * IDIM;
        pA0 = *(const float4*)(rpA + off); pA1 = *(const float4*)(rpA + off + 4);
        const float* rpB = zb + (size_t)((g < 2) ? (baseRow + 1) : iB0) * IDIM;
        pB0 = *(const float4*)(rpB + off); pB1 = *(const float4*)(rpB + off + 4);
    }

#pragma unroll 2
    for (int pp = 0; pp < PPB / 2; ++pp) {
        // prefetch next pair's features (indices from LDS, just-in-time)
        if (pp < PPB / 2 - 1) {
            int iA1 = sidx[(2 * pp + 2) * 16 + x];
            int iB1 = sidx[(2 * pp + 3) * 16 + x];
            const float* rpA = zb + (size_t)((g < 2) ? (baseRow + 2 * pp + 2) : iA1) * IDIM;
            nA0 = *(const float4*)(rpA + off); nA1 = *(const float4*)(rpA + off + 4);
            const float* rpB = zb + (size_t)((g < 2) ? (baseRow + 2 * pp + 3) : iB1) * IDIM;
            nB0 = *(const float4*)(rpB + off); nB1 = *(const float4*)(rpB + off + 4);
        }

        // pack features (v_cvt_pk_bf16_f32 pairs)
        union { bf16x8 v; unsigned w[4]; } efA, efB;
        efA.w[0] = pk2(pA0.x, pA0.y); efA.w[1] = pk2(pA0.z, pA0.w);
        efA.w[2] = pk2(pA1.x, pA1.y); efA.w[3] = pk2(pA1.z, pA1.w);
        efB.w[0] = pk2(pB0.x, pB0.y); efB.w[1] = pk2(pB0.z, pB0.w);
        efB.w[2] = pk2(pB1.x, pB1.y); efB.w[3] = pk2(pB1.z, pB1.w);

        // ---- L1 (bias in C; D and C are distinct MFMA operands) ----
        f32x4 aA[4], aB[4];
        __builtin_amdgcn_s_setprio(1);
#pragma unroll
        for (int c = 0; c < 4; ++c)
            aA[c] = __builtin_amdgcn_mfma_f32_16x16x32_bf16(a1[c], efA.v, b1v[c], 0, 0, 0);
#pragma unroll
        for (int c = 0; c < 4; ++c)
            aB[c] = __builtin_amdgcn_mfma_f32_16x16x32_bf16(a1[c], efB.v, b1v[c], 0, 0, 0);
        __builtin_amdgcn_s_setprio(0);
#pragma unroll
        for (int c = 0; c < 4; ++c) {
            union { unsigned w[2]; unsigned long long q; } qa;
            qa.w[0] = relu2(pk2(aA[c][0], aA[c][1]));
            qa.w[1] = relu2(pk2(aA[c][2], aA[c][3]));
            hq[baseA + woq[c]] = qa.q;
        }
#pragma unroll
        for (int c = 0; c < 4; ++c) {
            union { unsigned w[2]; unsigned long long q; } qb;
            qb.w[0] = relu2(pk2(aB[c][0], aB[c][1]));
            qb.w[1] = relu2(pk2(aB[c][2], aB[c][3]));
            hq[baseB + woq[c]] = qb.q;
        }

        // ---- read h1, L2 (bias in C) ----
        union { bf16x8 v; unsigned long long q[2]; } h0A, h1A, h0B, h1B;
        h0A.q[0] = hq[baseA + rq0]; h0A.q[1] = hq[baseA + rq0 + 1];
        h1A.q[0] = hq[baseA + rq1]; h1A.q[1] = hq[baseA + rq1 + 1];
        h0B.q[0] = hq[baseB + rq0]; h0B.q[1] = hq[baseB + rq0 + 1];
        h1B.q[0] = hq[baseB + rq1]; h1B.q[1] = hq[baseB + rq1 + 1];
        f32x4 cA[4], cB[4];
        __builtin_amdgcn_s_setprio(1);
#pragma unroll
        for (int c = 0; c < 4; ++c) {
            cA[c] = __builtin_amdgcn_mfma_f32_16x16x32_bf16(a2k0[c], h0A.v, b2v[c], 0, 0, 0);
            cB[c] = __builtin_amdgcn_mfma_f32_16x16x32_bf16(a2k0[c], h0B.v, b2v[c], 0, 0, 0);
        }
#pragma unroll
        for (int c = 0; c < 4; ++c) {
            cA[c] = __builtin_amdgcn_mfma_f32_16x16x32_bf16(a2k1[c], h1A.v, cA[c], 0, 0, 0);
            cB[c] = __builtin_amdgcn_mfma_f32_16x16x32_bf16(a2k1[c], h1B.v, cB[c], 0, 0, 0);
        }
        __builtin_amdgcn_s_setprio(0);
#pragma unroll
        for (int c = 0; c < 4; ++c) {
            union { unsigned w[2]; unsigned long long q; } qa;
            qa.w[0] = relu2(pk2(cA[c][0], cA[c][1]));
            qa.w[1] = relu2(pk2(cA[c][2], cA[c][3]));
            hq[baseA + woq[c]] = qa.q;
        }
#pragma unroll
        for (int c = 0; c < 4; ++c) {
            union { unsigned w[2]; unsigned long long q; } qb;
            qb.w[0] = relu2(pk2(cB[c][0], cB[c][1]));
            qb.w[1] = relu2(pk2(cB[c][2], cB[c][3]));
            hq[baseB + woq[c]] = qb.q;
        }

        // ---- read h2, L3 (bias in C) ----
        union { bf16x8 v; unsigned long long q[2]; } g0A, g1A, g0B, g1B;
        g0A.q[0] = hq[baseA + rq0]; g0A.q[1] = hq[baseA + rq0 + 1];
        g1A.q[0] = hq[baseA + rq1]; g1A.q[1] = hq[baseA + rq1 + 1];
        g0B.q[0] = hq[baseB + rq0]; g0B.q[1] = hq[baseB + rq0 + 1];
        g1B.q[0] = hq[baseB + rq1]; g1B.q[1] = hq[baseB + rq1 + 1];
        f32x4 oA, oB;
        __builtin_amdgcn_s_setprio(1);
        oA = __builtin_amdgcn_mfma_f32_16x16x32_bf16(a30, g0A.v, b3v, 0, 0, 0);
        oB = __builtin_amdgcn_mfma_f32_16x16x32_bf16(a30, g0B.v, b3v, 0, 0, 0);
        oA = __builtin_amdgcn_mfma_f32_16x16x32_bf16(a31, g1A.v, oA, 0, 0, 0);
        oB = __builtin_amdgcn_mfma_f32_16x16x32_bf16(a31, g1B.v, oB, 0, 0, 0);
        __builtin_amdgcn_s_setprio(0);

        // max over neighbors: raw ds_swizzle XOR tree
        float oA0 = red_max16(oA[0]), oA1 = red_max16(oA[1]);
        float oA2 = red_max16(oA[2]), oA3 = red_max16(oA[3]);
        float oB0 = red_max16(oB[0]), oB1 = red_max16(oB[1]);
        float oB2 = red_max16(oB[2]), oB3 = red_max16(oB[3]);

        if (x == 0) {
            *(float4*)&stg[((2 * pp + 0) * 4 + u) * 16 + 4 * g] = make_float4(oA0, oA1, oA2, oA3);
            *(float4*)&stg[((2 * pp + 1) * 4 + u) * 16 + 4 * g] = make_float4(oB0, oB1, oB2, oB3);
        }

        // rotate prefetched features
        pA0 = nA0; pA1 = nA1; pB0 = nB0; pB1 = nB1;
    }
    __syncthreads();

    // --- epilogue: z2 update + log_det (one atomic per block) ---
    {
        const int pu = u * 4 + g;                  // 0..15
        const int prow = pbase + pu;
        const size_t zoff = (size_t)prow * IDIM + 16 + x;
        float z2v = out[zoff];
        float s1 = stg[(pu * 4 + 0) * 16 + x];
        float t1 = stg[(pu * 4 + 1) * 16 + x];
        float s2 = stg[(pu * 4 + 2) * 16 + x];
        float t2 = stg[(pu * 4 + 3) * 16 + x];
        float sc1 = CLAMPV * TWO_OVER_PI * atanf(s1 * (1.0f / CLAMPV));
        float sc2 = CLAMPV * TWO_OVER_PI * atanf(s2 * (1.0f / CLAMPV));
        z2v = z2v * expf(sc1) + t1;
        z2v = z2v * expf(sc2) + t2;
        out[zoff] = z2v;
        float ss = red_sum16(sc1 + sc2);
        if (x == 0) ldsum[pu] = ss;
    }
    __syncthreads();
    if (tid == 0) {
        float tot = 0.f;
#pragma unroll
        for (int i = 0; i < 16; ++i) tot += ldsum[i];
        atomicAdd(out + (size_t)NBATCH * NPTS * IDIM + bb, tot);
    }
}

extern "C" void kernel_launch(void* const* d_in, const int* in_sizes, int n_in,
                              void* d_out, int out_size, void* d_ws, size_t ws_size,
                              hipStream_t stream) {
    const float* x    = (const float*)d_in[0];
    const int*   knn  = (const int*)d_in[1];
    const float* logs = (const float*)d_in[2];
    const float* bias = (const float*)d_in[3];
    const float* W1   = (const float*)d_in[4];
    const float* b1   = (const float*)d_in[5];
    const float* W2   = (const float*)d_in[6];
    const float* b2   = (const float*)d_in[7];
    const float* W3   = (const float*)d_in[8];
    const float* b3   = (const float*)d_in[9];
    float* out = (float*)d_out;
    unsigned short* wsb = (unsigned short*)d_ws;   // 56 frags * 1024 B = 57344 B

    hipLaunchKernelGGL(prep_frags, dim3(112), dim3(256), 0, stream, W1, W2, W3, wsb);
    hipLaunchKernelGGL(affine_rev, dim3(512), dim3(256), 0, stream, x, logs, bias, out);
    hipLaunchKernelGGL(knn_mfma, dim3((NBATCH * NPTS) / PPB), dim3(256), 0, stream,
                       knn, wsb, b1, b2, b3, out);
}